// Round 12
// baseline (80.425 us; speedup 1.0000x reference)
//
#include <hip/hip_runtime.h>

#define H 1024
#define N 64
#define L 2048
#define TPB 256
#define HALF_L 1024
#define NBLK (H * 2)      // 2 blocks per h, each covers 1024 l-positions
#define KPT 16            // l-positions per lane (stride 64 within the half)
#define NPW 16            // n's per wave (4 waves x 16 = 64)

#define INV2PI 0.15915494309189535f

typedef float f32x2 __attribute__((ext_vector_type(2)));

// complex multiply r = w * s, layout (re, im) = (lo, hi). Verified R1-R10.
__device__ __forceinline__ f32x2 cmul(f32x2 w, f32x2 s) {
    f32x2 t, r;
    asm("v_pk_mul_f32 %0, %1, %2 op_sel_hi:[1,0]"
        : "=v"(t) : "v"(w), "v"(s));
    asm("v_pk_fma_f32 %0, %1, %2, %3 op_sel:[1,1,0] op_sel_hi:[0,1,1] neg_lo:[1,0,0]"
        : "=v"(r) : "v"(w), "v"(s), "v"(t));
    return r;
}

__device__ __forceinline__ f32x2 cexp_rev(float mag_arg, float rev_arg) {
    float m = __expf(mag_arg);
    float rv = rev_arg - floorf(rev_arg);
    f32x2 e;
    e.x = m * __builtin_amdgcn_cosf(rv);
    e.y = m * __builtin_amdgcn_sinf(rv);
    return e;
}

// Theory: phase 2 of R6/R9 was LDS-PIPE-bound (per-n ds_reads in the hot loop;
// R6 model 15.4us vs 14.3 measured). This version removes LDS from the inner
// loop: phase 1 builds the FULL product table W0[n][j] = cm_n * r_n^(j+1024h)
// (32 KB, via 15-step cmul recurrence per thread), phase 2 preloads each
// wave's 16 per-lane w0 values into REGISTERS (16 batched conflict-free
// ds_read_b64), then runs a pure-VALU real 2nd-order recurrence
// u_k = 2a*u_{k-1} - |s|^2*u_{k-2} (s = r^64), 3 instr/term, with only a
// broadcast CF[n] read per n. Cross-wave n-sum via LDS partials overlaid on
// the dead W0 table.
__global__ __launch_bounds__(TPB, 4) void s4d_fused(const float* __restrict__ log_dt,
                                                    const float* __restrict__ Cv,
                                                    const float* __restrict__ Av,
                                                    float* __restrict__ out)
{
    __shared__ __align__(16) char smem[33792];   // W0 32KB + CF 1KB
    f32x2*  W0 = (f32x2*)smem;                   // [64][64]
    float4* CF = (float4*)(smem + 32768);        // [64]

    const int b    = blockIdx.x;
    const int h    = b >> 1;
    const int half = b & 1;
    const int t    = threadIdx.x;

    // ---------- phase 1: full W0 table (4 threads per n, 16 j's each) ----------
    {
        const int n = t >> 2;
        const int q = t & 3;
        float dt = __expf(log_dt[h]);

        float2 a2 = ((const float2*)Av)[n];
        float dr    = dt * a2.x;
        float direv = dt * a2.y * INV2PI;    // phase in revolutions per l

        // r1 = exp(dtA) — both the per-j step and the (e^dtA - 1) source
        f32x2 r1 = cexp_rev(dr, direv);

        // cm = 2 * C * (exp(dtA) - 1) / A
        float2 c2 = ((const float2*)Cv)[h * N + n];
        float er = r1.x - 1.0f, ei = r1.y;
        float tr = c2.x * er - c2.y * ei;
        float ti = c2.x * ei + c2.y * er;
        float inv = 2.0f / (a2.x * a2.x + a2.y * a2.y);
        f32x2 cm;
        cm.x = (tr * a2.x + ti * a2.y) * inv;
        cm.y = (ti * a2.x - tr * a2.y) * inv;

        // W0[n][16q .. 16q+15] by recurrence from an exact cexp start
        float fg = 16.0f * (float)q + 1024.0f * (float)half;
        f32x2 wv = cmul(cexp_rev(dr * fg, direv * fg), cm);
        f32x2* row = W0 + n * 64 + q * 16;
#pragma unroll
        for (int jj = 0; jj < 16; ++jj) {
            row[jj] = wv;
            wv = cmul(wv, r1);
        }

        if (q == 0) {   // CF[n] = (s.re, s.im, 2*s.re, -|s|^2), s = exp(dtA*64)
            f32x2 s = cexp_rev(dr * 64.0f, direv * 64.0f);
            CF[n] = make_float4(s.x, s.y, 2.0f * s.x, -(s.x * s.x + s.y * s.y));
        }
    }
    __syncthreads();

    // ---------- phase 2: register-resident, LDS-free inner loop ----------
    const int w  = t >> 6;        // wave id 0..3
    const int j  = t & 63;        // lane
    const int n0 = w * NPW;

    // Preload this wave's 16 per-lane w0 values (batched, conflict-free:
    // lane j reads row-consecutive 8B -> 2 lanes/bank, free per m136).
    f32x2 w0p[NPW];
#pragma unroll
    for (int ni = 0; ni < NPW; ++ni) w0p[ni] = W0[(n0 + ni) * 64 + j];

    float acc[KPT];
#pragma unroll
    for (int k = 0; k < KPT; ++k) acc[k] = 0.0f;

#pragma unroll
    for (int ni = 0; ni < NPW; ++ni) {           // fully unrolled: static w0p/acc idx
        float4 cf = CF[n0 + ni];                 // wave-uniform broadcast read
        float u0 = w0p[ni].x, v0 = w0p[ni].y;
        float u1 = u0 * cf.x - v0 * cf.y;        // Re(w0 * s)
        acc[0] += u0;
        acc[1] += u1;
#pragma unroll
        for (int k = 2; k < KPT; ++k) {
            float u2 = cf.z * u1 + cf.w * u0;    // 2a*u1 - |s|^2*u0
            acc[k] += u2;
            u0 = u1; u1 = u2;
        }
    }
    __syncthreads();    // all waves done reading W0 -> safe to overlay partials

    // ---------- cross-wave reduce via LDS partials ----------
    float* part = (float*)smem;          // [4][1024] f32 = 16 KB
#pragma unroll
    for (int k = 0; k < KPT; ++k)
        part[w * HALF_L + j + 64 * k] = acc[k];   // stride-1 per wave: 2/bank, free
    __syncthreads();

    float* o = out + h * L + (half << 10);
#pragma unroll
    for (int m = 0; m < 4; ++m) {
        int l = t + 256 * m;
        o[l] = part[l] + part[HALF_L + l] + part[2 * HALF_L + l] + part[3 * HALF_L + l];
    }
}

extern "C" void kernel_launch(void* const* d_in, const int* in_sizes, int n_in,
                              void* d_out, int out_size, void* d_ws, size_t ws_size,
                              hipStream_t stream) {
    const float* log_dt = (const float*)d_in[0];
    const float* Cv     = (const float*)d_in[1];   // (H, N, 2)
    const float* Av     = (const float*)d_in[2];   // (N, 2)
    float* out          = (float*)d_out;           // (H, L) fp32

    s4d_fused<<<NBLK, TPB, 0, stream>>>(log_dt, Cv, Av, out);
}